// Round 6
// baseline (1822.853 us; speedup 1.0000x reference)
//
#include <hip/hip_runtime.h>

typedef unsigned char u8;
typedef int i32x4 __attribute__((ext_vector_type(4)));
typedef int i32x16 __attribute__((ext_vector_type(16)));

#define C_DIM 640
#define HW_DIM 441
#define QN 75
#define SN 25
#define WAYS 5
#define MROWS 33075     // 75*441
#define MCH   128       // m rows per block
#define MBLK  259       // ceil(33075/128)
#define MPAD  33152     // MBLK*MCH
#define NWAY  2205      // 5*441
#define NPAD  2304      // 9*256
#define BN    256       // block n-tile
#define NT    9         // NPAD/BN
#define INV_Q2 (1.0f / 16129.0f)   // 1/127^2
#define NEGINF (-2147483647 - 1)

__device__ __forceinline__ void glds16(const void* g, void* l) {
  __builtin_amdgcn_global_load_lds(
      (__attribute__((address_space(1))) unsigned int*)g,
      (__attribute__((address_space(3))) unsigned int*)l, 16, 0, 0);
}

// 3-op sorted-top3 insert primitive: med3(v, hi, lo) == new lo-rank value.
__device__ __forceinline__ int med3i(int a, int b, int c) {
  int d;
  asm("v_med3_i32 %0, %1, %2, %3" : "=v"(d) : "v"(a), "v"(b), "v"(c));
  return d;
}

// ---------------------------------------------------------------------------
// Zero pad rows of A/B (int8 bytes) and the output accumulator.
// ---------------------------------------------------------------------------
__global__ void zero_pad(u8* __restrict__ A8, u8* __restrict__ S8,
                         float* __restrict__ out) {
  int i = blockIdx.x * 256 + threadIdx.x;
  if (i < 49280) {                                  // (MPAD-MROWS)*640 bytes
    A8[(size_t)MROWS * C_DIM + i] = 0;
    return;
  }
  i -= 49280;
  if (i < 316800) {                                 // 5*(NPAD-NWAY)*640 bytes
    const int w = i / 63360;
    const int r = i % 63360;
    S8[((size_t)w * NPAD + NWAY) * C_DIM + r] = 0;
    return;
  }
  i -= 316800;
  if (i < QN * WAYS) out[i] = 0.f;
}

// ---------------------------------------------------------------------------
// Normalize each (img, hw) descriptor over C, scale by 127, emit int8,
// transposed to [row][c] (c contiguous, 640 B/row). (unchanged)
// ---------------------------------------------------------------------------
__global__ __launch_bounds__(256)
void prep_norm_transpose(const float* __restrict__ src, u8* __restrict__ dst,
                         int support) {
  const int bid = blockIdx.x;
  const int img = bid / 7;
  const int mt = bid % 7;
  const int m0 = mt * 64;
  const int t = threadIdx.x;
  const int mloc = t & 63;
  const int cpart = t >> 6;                 // 0..3
  const int m = m0 + mloc;
  const int m_eff = (m < HW_DIM) ? m : (HW_DIM - 1);
  const float* base = src + (size_t)img * (C_DIM * HW_DIM);

  float ss = 0.f;
  const int c0 = cpart * 160;
  for (int c = c0; c < c0 + 160; ++c) {
    float v = base[(size_t)c * HW_DIM + m_eff];
    ss += v * v;
  }
  __shared__ float red[256];
  __shared__ float inv[64];
  red[t] = ss;
  __syncthreads();
  if (t < 64) {
    float s4 = red[t] + red[t + 64] + red[t + 128] + red[t + 192];
    inv[t] = rsqrtf(s4) * 127.0f;
  }
  __syncthreads();

  size_t drow0;
  if (support) {
    const int w = img / 5, shot = img % 5;
    drow0 = (size_t)w * NPAD + (size_t)shot * HW_DIM;
  } else {
    drow0 = (size_t)img * HW_DIM;
  }

  __shared__ __align__(16) u8 T[64][80];    // 64 data + 16 pad per row
  const float iv = inv[mloc];
  const int mw = t >> 2;
  const int cg = t & 3;
  const int m_out = m0 + mw;

  for (int ct = 0; ct < 10; ++ct) {
    int q[16];
#pragma unroll
    for (int ci = 0; ci < 16; ++ci) {
      const int c = ct * 64 + cpart * 16 + ci;
      q[ci] = __float2int_rn(base[(size_t)c * HW_DIM + m_eff] * iv);
    }
    __syncthreads();                        // previous tile fully consumed
    uint4 w;
    w.x = (q[0] & 255) | ((q[1] & 255) << 8) | ((q[2] & 255) << 16) | ((q[3] & 255) << 24);
    w.y = (q[4] & 255) | ((q[5] & 255) << 8) | ((q[6] & 255) << 16) | ((q[7] & 255) << 24);
    w.z = (q[8] & 255) | ((q[9] & 255) << 8) | ((q[10] & 255) << 16) | ((q[11] & 255) << 24);
    w.w = (q[12] & 255) | ((q[13] & 255) << 8) | ((q[14] & 255) << 16) | ((q[15] & 255) << 24);
    *(uint4*)&T[mloc][cpart * 16] = w;
    __syncthreads();
    if (m_out < HW_DIM) {
      const uint4 v = *(const uint4*)&T[mw][cg * 16];
      *(uint4*)(dst + (drow0 + m_out) * C_DIM + ct * 64 + cg * 16) = v;
    }
  }
}

// ---------------------------------------------------------------------------
// Fused cosine-sim GEMM (int8 mfma_i32_32x32x32) + per-row top-3 + sum.
// Round-13: 8-wave block = 2 waves/SIMD co-residency (the R0-proven
// regime) + R4's low-traffic tile.
//  - Evidence R0/R4/R5: the per-phase barrier critical path is ~4000 cyc
//    regardless of sync flavor (syncthreads 3871, counted-vmcnt 4860);
//    MFMA-busy inside it is only ~550. The ONLY config that amortized it
//    was 2 waves/SIMD (R0: 27% MfmaUtil). R4's tile can't fit 2 blocks
//    (228 reg x 2 > 512 unified budget at 4 waves) -- but ONE 8-wave
//    block gives 2 waves/SIMD: 2 x 228 = 456 <= 512.
//  - Wave tile 64m x 64n (acc 64 + top3 96 + A ping-pong 64 ~ 228 regs,
//    spill-free, verified R4/R5). Waves arranged 2m x 4n ->
//    block tile 128m x 256n. BN=256, NT=9, 45 phases/block.
//  - Per-CU phase: MFMA 2x16x36.6 ~ 1171 cyc/SIMD; LDS 96 KB ~ 1050;
//    while one wave is in its MFMA burst the SIMD-sibling issues its
//    ds_read/VMEM -> pipes stay fed inside one barrier domain.
//  - Plain __syncthreads (R5 falsified the hand-pinned variant); A
//    prefetched one kt ahead into ping-pong regs, issued pre-MFMA.
// Grid: 5 ways * 259 m-chunks = 1295 blocks of 512 threads.
// ---------------------------------------------------------------------------
__global__ __launch_bounds__(512, 2)
void simtopk(const u8* __restrict__ A8, const u8* __restrict__ S8,
             float* __restrict__ out) {
  __shared__ __align__(16) u8 Bs[2][BN * 128];      // 64 KB B double buffer
  __shared__ float qsum[2];

  const int bid = blockIdx.x;
  const int way = bid / MBLK;
  const int mc = bid % MBLK;
  const int R0 = mc * MCH;
  const int tid = threadIdx.x;
  const int lane = tid & 63;
  const int wv = tid >> 6;                  // 0..7
  const int wm = (wv >> 2) * 64;            // wave m base: 0 / 64
  const int wc = wv & 3;                    // n-quadrant: 0..3
  const int wnB = wc * 64;                  // wave n base within BN=256
  const int r5 = lane & 31;
  const int h = lane >> 5;                  // k-half selector

  if (tid < 2) qsum[tid] = 0.f;

  const u8* Sway = S8 + (size_t)way * NPAD * C_DIM;

  // ---- A row bases for this lane's two rows (r5, r5+32 within wave tile).
  const u8* Ar0 = A8 + (size_t)(R0 + wm + r5) * C_DIM + h * 16;
  const u8* Ar1 = Ar0 + 32 * C_DIM;

  // A ping-pong: phase kt uses (kt&1 ? aQ : aP).
  i32x4 aP[8], aQ[8];
#pragma unroll
  for (int s = 0; s < 4; ++s) {             // prologue: kt=0 -> aP
    aP[s]     = *(const i32x4*)(Ar0 + s * 32);
    aP[4 + s] = *(const i32x4*)(Ar1 + s * 32);
  }

  // ---- B staging: strip = 8 rows x 128 B = 1 KB per instruction;
  // 32 strips per phase (BN=256), 4 per wave. Source-side XOR swizzle.
  const unsigned brow =
      (unsigned)((lane >> 3) * 640 + (((lane & 7) ^ (lane >> 3)) * 16));
#pragma unroll
  for (int j = 0; j < 4; ++j) {             // prologue: phase 0 -> Bs[0]
    const int st = wv * 4 + j;
    glds16(Sway + (unsigned)st * (8 * 640) + brow, Bs[0] + st * 1024);
  }

  // ---- precomputed B-frag LDS offsets (b128, swizzled, conflict-free) ----
  int bBase[2], pqs[4];
#pragma unroll
  for (int ni = 0; ni < 2; ++ni)
    bBase[ni] = (wnB + ni * 32 + r5) * 128;
#pragma unroll
  for (int s = 0; s < 4; ++s)
    pqs[s] = ((2 * s + h) ^ (r5 & 7)) * 16;

  i32x16 acc[2][2];
#pragma unroll
  for (int mi = 0; mi < 2; ++mi)
#pragma unroll
    for (int ni = 0; ni < 2; ++ni)
#pragma unroll
      for (int g = 0; g < 16; ++g) acc[mi][ni][g] = 0;

  int t0[32], t1[32], t2[32];               // per-lane top-3, 32 row slots
#pragma unroll
  for (int r = 0; r < 32; ++r) { t0[r] = NEGINF; t1[r] = NEGINF; t2[r] = NEGINF; }

// PRE: A-prefetch before MFMAs (targets other buffer). POST: after (kt==4).
#define PHASE(KT, CUR, NXT, PRE)                                              \
  {                                                                           \
    __syncthreads(); /* Bs[p] staged; Bs[p^1] free; A prefetch landed */      \
    const bool lastph = (nt == NT - 1) && ((KT) == 4);                        \
    const int kt1 = ((KT) == 4) ? 0 : ((KT) + 1);                             \
    if (!lastph) { /* B prefetch next phase -> Bs[p^1] */                     \
      const int nt1 = ((KT) == 4) ? nt + 1 : nt;                              \
      const unsigned off =                                                    \
          (unsigned)nt1 * (BN * C_DIM) + (unsigned)(kt1 * 128);               \
      _Pragma("unroll")                                                       \
      for (int j = 0; j < 4; ++j) {                                           \
        const int st = wv * 4 + j;                                            \
        glds16(Sway + (unsigned)st * (8 * 640) + brow + off,                  \
               Bs[p ^ 1] + st * 1024);                                        \
      }                                                                       \
    }                                                                         \
    if ((PRE) && !lastph) {                                                   \
      _Pragma("unroll")                                                       \
      for (int s = 0; s < 4; ++s) {                                           \
        NXT[s]     = *(const i32x4*)(Ar0 + kt1 * 128 + s * 32);               \
        NXT[4 + s] = *(const i32x4*)(Ar1 + kt1 * 128 + s * 32);               \
      }                                                                       \
    }                                                                         \
    const u8* Bp = Bs[p];                                                     \
    _Pragma("unroll")                                                         \
    for (int s = 0; s < 4; ++s) {                                             \
      const i32x4 av0 = CUR[s];                                               \
      const i32x4 av1 = CUR[4 + s];                                           \
      const i32x4 b0v = *(const i32x4*)(Bp + bBase[0] + pqs[s]);              \
      const i32x4 b1v = *(const i32x4*)(Bp + bBase[1] + pqs[s]);              \
      acc[0][0] = __builtin_amdgcn_mfma_i32_32x32x32_i8(av0, b0v, acc[0][0], 0, 0, 0); \
      acc[1][0] = __builtin_amdgcn_mfma_i32_32x32x32_i8(av1, b0v, acc[1][0], 0, 0, 0); \
      acc[0][1] = __builtin_amdgcn_mfma_i32_32x32x32_i8(av0, b1v, acc[0][1], 0, 0, 0); \
      acc[1][1] = __builtin_amdgcn_mfma_i32_32x32x32_i8(av1, b1v, acc[1][1], 0, 0, 0); \
    }                                                                         \
    if (!(PRE) && !lastph) { /* kt==4: self-target aP, must follow MFMAs */   \
      _Pragma("unroll")                                                       \
      for (int s = 0; s < 4; ++s) {                                           \
        NXT[s]     = *(const i32x4*)(Ar0 + kt1 * 128 + s * 32);               \
        NXT[4 + s] = *(const i32x4*)(Ar1 + kt1 * 128 + s * 32);               \
      }                                                                       \
    }                                                                         \
    p ^= 1;                                                                   \
  }

  int p = 0;
  for (int nt = 0; nt < NT; ++nt) {
    PHASE(0, aP, aQ, 1)
    PHASE(1, aQ, aP, 1)
    PHASE(2, aP, aQ, 1)
    PHASE(3, aQ, aP, 1)
    PHASE(4, aP, aP, 0)  // successor is next nt's kt=0, which uses aP

    // end of nt: branchless int top-3 insert (3 ops via med3), re-zero acc.
    // C/D 32x32: col = r5 (-> n), row = (g&3) + 8*(g>>2) + 4*h (+ wm + 32*mi).
    if (nt != NT - 1) {
#pragma unroll
      for (int mi = 0; mi < 2; ++mi)
#pragma unroll
        for (int ni = 0; ni < 2; ++ni)
#pragma unroll
          for (int g = 0; g < 16; ++g) {
            const int v = acc[mi][ni][g];
            const int r = mi * 16 + g;
            t2[r] = med3i(v, t1[r], t2[r]);
            t1[r] = med3i(v, t0[r], t1[r]);
            t0[r] = max(t0[r], v);
            acc[mi][ni][g] = 0;
          }
    } else {                                // last tile: mask pad columns
#pragma unroll
      for (int mi = 0; mi < 2; ++mi)
#pragma unroll
        for (int ni = 0; ni < 2; ++ni) {
          const int ncol = nt * BN + wnB + ni * 32 + r5;
          const bool bad = (ncol >= NWAY);
#pragma unroll
          for (int g = 0; g < 16; ++g) {
            int v = acc[mi][ni][g];
            if (bad) v = NEGINF;
            const int r = mi * 16 + g;
            t2[r] = med3i(v, t1[r], t2[r]);
            t1[r] = med3i(v, t0[r], t1[r]);
            t0[r] = max(t0[r], v);
          }
        }
    }
  }
#undef PHASE

  // ---- partial butterfly over column-lanes d=1,2 (stays in 32-lane half)
#pragma unroll
  for (int d = 1; d <= 2; d <<= 1) {
#pragma unroll
    for (int r = 0; r < 32; ++r) {
      const int o0 = __shfl_xor(t0[r], d);
      const int o1 = __shfl_xor(t1[r], d);
      const int o2 = __shfl_xor(t2[r], d);
      t2[r] = med3i(o0, t1[r], t2[r]);
      t1[r] = med3i(o0, t0[r], t1[r]);
      t0[r] = max(t0[r], o0);
      t2[r] = med3i(o1, t1[r], t2[r]);
      t1[r] = med3i(o1, t0[r], t1[r]);
      t0[r] = max(t0[r], o1);
      t2[r] = med3i(o2, t1[r], t2[r]);
      t1[r] = med3i(o2, t0[r], t1[r]);
      t0[r] = max(t0[r], o2);
    }
  }

  // dump partials to LDS aliased over Bs: 32 col-groups (4 wc x 8 lane-grp)
  // x 128 rows x i32x4 = 64 KB. XOR swizzle (row ^ (grp&7)) keeps both
  // write and read patterns conflict-light.
  __syncthreads();                          // all B-tile reads complete
  int* part = (int*)&Bs[0][0];              // part[grp][row][4] : 64 KB
  if ((r5 & 3) == 0) {
    const int grp = wc * 8 + (r5 >> 2);     // 0..31
#pragma unroll
    for (int r = 0; r < 32; ++r) {
      const int mi = r >> 4;
      const int g = r & 15;
      const int row_local = wm + mi * 32 + (g & 3) + 8 * (g >> 2) + 4 * h;
      i32x4 v;
      v[0] = t0[r]; v[1] = t1[r]; v[2] = t2[r]; v[3] = NEGINF;
      *(i32x4*)&part[(grp * MCH + (row_local ^ (grp & 7))) * 4] = v;
    }
  }
  __syncthreads();
  if (tid < MCH) {
    const int grow = R0 + tid;
    if (grow < MROWS) {
      int a0_ = NEGINF, a1_ = NEGINF, a2_ = NEGINF;
#pragma unroll 4
      for (int g = 0; g < 32; ++g) {
        const i32x4 v = *(const i32x4*)&part[(g * MCH + (tid ^ (g & 7))) * 4];
        a2_ = med3i(v[0], a1_, a2_); a1_ = med3i(v[0], a0_, a1_); a0_ = max(a0_, v[0]);
        a2_ = med3i(v[1], a1_, a2_); a1_ = med3i(v[1], a0_, a1_); a0_ = max(a0_, v[1]);
        a2_ = med3i(v[2], a1_, a2_); a1_ = med3i(v[2], a0_, a1_); a0_ = max(a0_, v[2]);
      }
      const float rs = (float)(a0_ + a1_ + a2_) * INV_Q2;
      const int qq = grow / HW_DIM;
      atomicAdd(&qsum[qq - (R0 / HW_DIM)], rs);     // block spans <= 2 q's
    }
  }
  __syncthreads();
  if (tid < 2) {
    const int qq = R0 / HW_DIM + tid;
    if (qq < QN) atomicAdd(out + qq * WAYS + way, qsum[tid]);
  }
}

// ---------------------------------------------------------------------------
extern "C" void kernel_launch(void* const* d_in, const int* in_sizes, int n_in,
                              void* d_out, int out_size, void* d_ws, size_t ws_size,
                              hipStream_t stream) {
  const float* x1 = (const float*)d_in[0];
  const float* x2 = (const float*)d_in[1];
  float* out = (float*)d_out;
  u8* A8 = (u8*)d_ws;                                        // MPAD x 640 i8
  u8* S8 = (u8*)d_ws + (size_t)MPAD * C_DIM;                 // 5 x NPAD x 640

  hipLaunchKernelGGL(zero_pad, dim3(1432), dim3(256), 0, stream, A8, S8, out);
  hipLaunchKernelGGL(prep_norm_transpose, dim3(QN * 7), dim3(256), 0, stream,
                     x1, A8, 0);
  hipLaunchKernelGGL(prep_norm_transpose, dim3(SN * 7), dim3(256), 0, stream,
                     x2, S8, 1);
  hipLaunchKernelGGL(simtopk, dim3(WAYS * MBLK), dim3(512), 0, stream,
                     A8, S8, out);
}

// Round 7
// 1711.443 us; speedup vs baseline: 1.0651x; 1.0651x over previous
//
#include <hip/hip_runtime.h>

typedef unsigned char u8;
typedef int i32x4 __attribute__((ext_vector_type(4)));
typedef int i32x16 __attribute__((ext_vector_type(16)));

#define C_DIM 640
#define HW_DIM 441
#define QN 75
#define SN 25
#define WAYS 5
#define MROWS 33075     // 75*441
#define MCH   128       // m rows per block
#define MBLK  259       // ceil(33075/128)
#define MPAD  33152     // MBLK*MCH
#define NWAY  2205      // 5*441
#define NPAD  2304      // 18*128
#define BN    128       // block n-tile
#define NT    18        // NPAD/BN
#define INV_Q2 (1.0f / 16129.0f)   // 1/127^2
#define NEGINF (-2147483647 - 1)

__device__ __forceinline__ void glds16(const void* g, void* l) {
  __builtin_amdgcn_global_load_lds(
      (__attribute__((address_space(1))) unsigned int*)g,
      (__attribute__((address_space(3))) unsigned int*)l, 16, 0, 0);
}

// 3-op sorted-top3 insert primitive: med3(v, hi, lo) == new lo-rank value.
__device__ __forceinline__ int med3i(int a, int b, int c) {
  int d;
  asm("v_med3_i32 %0, %1, %2, %3" : "=v"(d) : "v"(a), "v"(b), "v"(c));
  return d;
}

// ---------------------------------------------------------------------------
// Zero pad rows of A/B (int8 bytes) and the output accumulator.
// ---------------------------------------------------------------------------
__global__ void zero_pad(u8* __restrict__ A8, u8* __restrict__ S8,
                         float* __restrict__ out) {
  int i = blockIdx.x * 256 + threadIdx.x;
  if (i < 49280) {                                  // (MPAD-MROWS)*640 bytes
    A8[(size_t)MROWS * C_DIM + i] = 0;
    return;
  }
  i -= 49280;
  if (i < 316800) {                                 // 5*(NPAD-NWAY)*640 bytes
    const int w = i / 63360;
    const int r = i % 63360;
    S8[((size_t)w * NPAD + NWAY) * C_DIM + r] = 0;
    return;
  }
  i -= 316800;
  if (i < QN * WAYS) out[i] = 0.f;
}

// ---------------------------------------------------------------------------
// Normalize each (img, hw) descriptor over C, scale by 127, emit int8,
// transposed to [row][c] (c contiguous, 640 B/row). (unchanged)
// ---------------------------------------------------------------------------
__global__ __launch_bounds__(256)
void prep_norm_transpose(const float* __restrict__ src, u8* __restrict__ dst,
                         int support) {
  const int bid = blockIdx.x;
  const int img = bid / 7;
  const int mt = bid % 7;
  const int m0 = mt * 64;
  const int t = threadIdx.x;
  const int mloc = t & 63;
  const int cpart = t >> 6;                 // 0..3
  const int m = m0 + mloc;
  const int m_eff = (m < HW_DIM) ? m : (HW_DIM - 1);
  const float* base = src + (size_t)img * (C_DIM * HW_DIM);

  float ss = 0.f;
  const int c0 = cpart * 160;
  for (int c = c0; c < c0 + 160; ++c) {
    float v = base[(size_t)c * HW_DIM + m_eff];
    ss += v * v;
  }
  __shared__ float red[256];
  __shared__ float inv[64];
  red[t] = ss;
  __syncthreads();
  if (t < 64) {
    float s4 = red[t] + red[t + 64] + red[t + 128] + red[t + 192];
    inv[t] = rsqrtf(s4) * 127.0f;
  }
  __syncthreads();

  size_t drow0;
  if (support) {
    const int w = img / 5, shot = img % 5;
    drow0 = (size_t)w * NPAD + (size_t)shot * HW_DIM;
  } else {
    drow0 = (size_t)img * HW_DIM;
  }

  __shared__ __align__(16) u8 T[64][80];    // 64 data + 16 pad per row
  const float iv = inv[mloc];
  const int mw = t >> 2;
  const int cg = t & 3;
  const int m_out = m0 + mw;

  for (int ct = 0; ct < 10; ++ct) {
    int q[16];
#pragma unroll
    for (int ci = 0; ci < 16; ++ci) {
      const int c = ct * 64 + cpart * 16 + ci;
      q[ci] = __float2int_rn(base[(size_t)c * HW_DIM + m_eff] * iv);
    }
    __syncthreads();                        // previous tile fully consumed
    uint4 w;
    w.x = (q[0] & 255) | ((q[1] & 255) << 8) | ((q[2] & 255) << 16) | ((q[3] & 255) << 24);
    w.y = (q[4] & 255) | ((q[5] & 255) << 8) | ((q[6] & 255) << 16) | ((q[7] & 255) << 24);
    w.z = (q[8] & 255) | ((q[9] & 255) << 8) | ((q[10] & 255) << 16) | ((q[11] & 255) << 24);
    w.w = (q[12] & 255) | ((q[13] & 255) << 8) | ((q[14] & 255) << 16) | ((q[15] & 255) << 24);
    *(uint4*)&T[mloc][cpart * 16] = w;
    __syncthreads();
    if (m_out < HW_DIM) {
      const uint4 v = *(const uint4*)&T[mw][cg * 16];
      *(uint4*)(dst + (drow0 + m_out) * C_DIM + ct * 64 + cg * 16) = v;
    }
  }
}

// ---------------------------------------------------------------------------
// Fused cosine-sim GEMM (int8 mfma_i32_32x32x32) + per-row top-3 + sum.
// Round-14: the register budget is now designed around the HARD rule
// confirmed by R2/R6: 2 waves/SIMD <=> (arch + acc) <= 256 unified/wave.
//  - Wave tile 64m x 64n (B frag -> 2 MFMAs, halved LDS traffic vs R0):
//      acc 2x2 i32x16          = 64
//      top-3 t0/t1/t2[32]      = 96
//      A single buffer a[8]    = 32   (ping-pong dropped: R6 lesson)
//      B temps + addressing    ~ 30
//      total                   ~ 222 <= 256  -> no spill at (256,2)
//  - __launch_bounds__(256,2): TWO independent 4-wave blocks per CU in
//    staggered barrier domains -- the only mechanism that has ever
//    amortized the ~2000-cyc phase wall (R0: 27% MfmaUtil; R4/R5 at
//    1 block/CU: 13.5%/10.7%).
//  - A for the next kt loaded AFTER the MFMA burst (WAR-safe on the
//    single buffer); the next __syncthreads' vmcnt(0) drain completes
//    it for free -- same mechanics as R4's kt==4 path, zero stall in
//    the consuming phase.
//  - Plain __syncthreads (R5 falsified hand-pinned vmcnt scheduling).
// Grid: 5 ways * 259 m-chunks = 1295 blocks of 256 threads.
// ---------------------------------------------------------------------------
__global__ __launch_bounds__(256, 2)
void simtopk(const u8* __restrict__ A8, const u8* __restrict__ S8,
             float* __restrict__ out) {
  __shared__ __align__(16) u8 Bs[2][BN * 128];      // 32 KB B double buffer
  __shared__ float qsum[2];

  const int bid = blockIdx.x;
  const int way = bid / MBLK;
  const int mc = bid % MBLK;
  const int R0 = mc * MCH;
  const int tid = threadIdx.x;
  const int lane = tid & 63;
  const int wv = tid >> 6;                  // 0..3
  const int wm = (wv >> 1) * 64;            // wave m base: 0 / 64
  const int nh = wv & 1;                    // n-half: 0 / 1
  const int wnB = nh * 64;                  // wave n base within BN=128
  const int r5 = lane & 31;
  const int h = lane >> 5;                  // k-half selector

  if (tid < 2) qsum[tid] = 0.f;

  const u8* Sway = S8 + (size_t)way * NPAD * C_DIM;

  // ---- A row bases for this lane's two rows (r5, r5+32 within wave tile).
  const u8* Ar0 = A8 + (size_t)(R0 + wm + r5) * C_DIM + h * 16;
  const u8* Ar1 = Ar0 + 32 * C_DIM;

  // Single A buffer: holds current kt's fragments (2 rows x 4 k-slices).
  i32x4 a[8];
#pragma unroll
  for (int s = 0; s < 4; ++s) {             // prologue: kt=0
    a[s]     = *(const i32x4*)(Ar0 + s * 32);
    a[4 + s] = *(const i32x4*)(Ar1 + s * 32);
  }

  // ---- B staging: strip = 8 rows x 128 B = 1 KB per instruction;
  // 16 strips per phase (BN=128), 4 per wave. Source-side XOR swizzle.
  const unsigned brow =
      (unsigned)((lane >> 3) * 640 + (((lane & 7) ^ (lane >> 3)) * 16));
#pragma unroll
  for (int j = 0; j < 4; ++j) {             // prologue: phase 0 -> Bs[0]
    const int st = wv * 4 + j;
    glds16(Sway + (unsigned)st * (8 * 640) + brow, Bs[0] + st * 1024);
  }

  // ---- precomputed B-frag LDS offsets (b128, swizzled, conflict-free) ----
  int bBase[2], pqs[4];
#pragma unroll
  for (int ni = 0; ni < 2; ++ni)
    bBase[ni] = (wnB + ni * 32 + r5) * 128;
#pragma unroll
  for (int s = 0; s < 4; ++s)
    pqs[s] = ((2 * s + h) ^ (r5 & 7)) * 16;

  i32x16 acc[2][2];
#pragma unroll
  for (int mi = 0; mi < 2; ++mi)
#pragma unroll
    for (int ni = 0; ni < 2; ++ni)
#pragma unroll
      for (int g = 0; g < 16; ++g) acc[mi][ni][g] = 0;

  int t0[32], t1[32], t2[32];               // per-lane top-3, 32 row slots
#pragma unroll
  for (int r = 0; r < 32; ++r) { t0[r] = NEGINF; t1[r] = NEGINF; t2[r] = NEGINF; }

  int p = 0;
  for (int nt = 0; nt < NT; ++nt) {
#pragma unroll
    for (int kt = 0; kt < 5; ++kt) {
      __syncthreads();  // Bs[p] staged & a[] loaded (drained by barrier)

      const bool lastph = (nt == NT - 1) && (kt == 4);
      const int kt1 = (kt == 4) ? 0 : kt + 1;

      if (!lastph) {    // B prefetch next phase -> Bs[p^1]
        const int nt1 = (kt == 4) ? nt + 1 : nt;
        const unsigned off =
            (unsigned)nt1 * (BN * C_DIM) + (unsigned)(kt1 * 128);
#pragma unroll
        for (int j = 0; j < 4; ++j) {
          const int st = wv * 4 + j;
          glds16(Sway + (unsigned)st * (8 * 640) + brow + off,
                 Bs[p ^ 1] + st * 1024);
        }
      }

      const u8* Bp = Bs[p];
#pragma unroll
      for (int s = 0; s < 4; ++s) {
        const i32x4 av0 = a[s];
        const i32x4 av1 = a[4 + s];
        const i32x4 b0v = *(const i32x4*)(Bp + bBase[0] + pqs[s]);
        const i32x4 b1v = *(const i32x4*)(Bp + bBase[1] + pqs[s]);
        acc[0][0] = __builtin_amdgcn_mfma_i32_32x32x32_i8(av0, b0v, acc[0][0], 0, 0, 0);
        acc[1][0] = __builtin_amdgcn_mfma_i32_32x32x32_i8(av1, b0v, acc[1][0], 0, 0, 0);
        acc[0][1] = __builtin_amdgcn_mfma_i32_32x32x32_i8(av0, b1v, acc[0][1], 0, 0, 0);
        acc[1][1] = __builtin_amdgcn_mfma_i32_32x32x32_i8(av1, b1v, acc[1][1], 0, 0, 0);
      }

      if (!lastph) {    // A load for kt1 (WAR-safe: after all MFMA reads)
#pragma unroll
        for (int s = 0; s < 4; ++s) {
          a[s]     = *(const i32x4*)(Ar0 + kt1 * 128 + s * 32);
          a[4 + s] = *(const i32x4*)(Ar1 + kt1 * 128 + s * 32);
        }
      }
      p ^= 1;
    }

    // end of nt: branchless int top-3 insert (3 ops via med3), re-zero acc.
    // C/D 32x32: col = r5 (-> n), row = (g&3) + 8*(g>>2) + 4*h (+ wm + 32*mi).
    if (nt != NT - 1) {
#pragma unroll
      for (int mi = 0; mi < 2; ++mi)
#pragma unroll
        for (int ni = 0; ni < 2; ++ni)
#pragma unroll
          for (int g = 0; g < 16; ++g) {
            const int v = acc[mi][ni][g];
            const int r = mi * 16 + g;
            t2[r] = med3i(v, t1[r], t2[r]);
            t1[r] = med3i(v, t0[r], t1[r]);
            t0[r] = max(t0[r], v);
            acc[mi][ni][g] = 0;
          }
    } else {                                // last tile: mask pad columns
#pragma unroll
      for (int mi = 0; mi < 2; ++mi)
#pragma unroll
        for (int ni = 0; ni < 2; ++ni) {
          const int ncol = nt * BN + wnB + ni * 32 + r5;
          const bool bad = (ncol >= NWAY);
#pragma unroll
          for (int g = 0; g < 16; ++g) {
            int v = acc[mi][ni][g];
            if (bad) v = NEGINF;
            const int r = mi * 16 + g;
            t2[r] = med3i(v, t1[r], t2[r]);
            t1[r] = med3i(v, t0[r], t1[r]);
            t0[r] = max(t0[r], v);
          }
        }
    }
  }

  // ---- partial butterfly over column-lanes d=1,2 (stays in 32-lane half)
#pragma unroll
  for (int d = 1; d <= 2; d <<= 1) {
#pragma unroll
    for (int r = 0; r < 32; ++r) {
      const int o0 = __shfl_xor(t0[r], d);
      const int o1 = __shfl_xor(t1[r], d);
      const int o2 = __shfl_xor(t2[r], d);
      t2[r] = med3i(o0, t1[r], t2[r]);
      t1[r] = med3i(o0, t0[r], t1[r]);
      t0[r] = max(t0[r], o0);
      t2[r] = med3i(o1, t1[r], t2[r]);
      t1[r] = med3i(o1, t0[r], t1[r]);
      t0[r] = max(t0[r], o1);
      t2[r] = med3i(o2, t1[r], t2[r]);
      t1[r] = med3i(o2, t0[r], t1[r]);
      t0[r] = max(t0[r], o2);
    }
  }

  // dump 32 partials/row-slot (2 nh x 8 col-groups = 16 grp) to LDS over Bs.
  // XOR swizzle (row ^ (grp&7)) keeps write/read patterns conflict-light.
  __syncthreads();                          // all B-tile reads complete
  int* part = (int*)&Bs[0][0];              // part[grp][row][4] : 32 KB
  if ((r5 & 3) == 0) {
    const int grp = nh * 8 + (r5 >> 2);     // 0..15
#pragma unroll
    for (int r = 0; r < 32; ++r) {
      const int mi = r >> 4;
      const int g = r & 15;
      const int row_local = wm + mi * 32 + (g & 3) + 8 * (g >> 2) + 4 * h;
      i32x4 v;
      v[0] = t0[r]; v[1] = t1[r]; v[2] = t2[r]; v[3] = NEGINF;
      *(i32x4*)&part[(grp * MCH + (row_local ^ (grp & 7))) * 4] = v;
    }
  }
  __syncthreads();
  if (tid < MCH) {
    const int grow = R0 + tid;
    if (grow < MROWS) {
      int a0_ = NEGINF, a1_ = NEGINF, a2_ = NEGINF;
#pragma unroll 4
      for (int g = 0; g < 16; ++g) {
        const i32x4 v = *(const i32x4*)&part[(g * MCH + (tid ^ (g & 7))) * 4];
        a2_ = med3i(v[0], a1_, a2_); a1_ = med3i(v[0], a0_, a1_); a0_ = max(a0_, v[0]);
        a2_ = med3i(v[1], a1_, a2_); a1_ = med3i(v[1], a0_, a1_); a0_ = max(a0_, v[1]);
        a2_ = med3i(v[2], a1_, a2_); a1_ = med3i(v[2], a0_, a1_); a0_ = max(a0_, v[2]);
      }
      const float rs = (float)(a0_ + a1_ + a2_) * INV_Q2;
      const int qq = grow / HW_DIM;
      atomicAdd(&qsum[qq - (R0 / HW_DIM)], rs);     // block spans <= 2 q's
    }
  }
  __syncthreads();
  if (tid < 2) {
    const int qq = R0 / HW_DIM + tid;
    if (qq < QN) atomicAdd(out + qq * WAYS + way, qsum[tid]);
  }
}

// ---------------------------------------------------------------------------
extern "C" void kernel_launch(void* const* d_in, const int* in_sizes, int n_in,
                              void* d_out, int out_size, void* d_ws, size_t ws_size,
                              hipStream_t stream) {
  const float* x1 = (const float*)d_in[0];
  const float* x2 = (const float*)d_in[1];
  float* out = (float*)d_out;
  u8* A8 = (u8*)d_ws;                                        // MPAD x 640 i8
  u8* S8 = (u8*)d_ws + (size_t)MPAD * C_DIM;                 // 5 x NPAD x 640

  hipLaunchKernelGGL(zero_pad, dim3(1432), dim3(256), 0, stream, A8, S8, out);
  hipLaunchKernelGGL(prep_norm_transpose, dim3(QN * 7), dim3(256), 0, stream,
                     x1, A8, 0);
  hipLaunchKernelGGL(prep_norm_transpose, dim3(SN * 7), dim3(256), 0, stream,
                     x2, S8, 1);
  hipLaunchKernelGGL(simtopk, dim3(WAYS * MBLK), dim3(256), 0, stream,
                     A8, S8, out);
}

// Round 8
// 1039.999 us; speedup vs baseline: 1.7527x; 1.6456x over previous
//
#include <hip/hip_runtime.h>

typedef unsigned char u8;
typedef int i32x4 __attribute__((ext_vector_type(4)));

#define C_DIM 640
#define HW_DIM 441
#define QN 75
#define SN 25
#define WAYS 5
#define MROWS 33075     // 75*441
#define MCH   128       // m rows per block
#define MBLK  259       // ceil(33075/128)
#define MPAD  33152     // MBLK*MCH
#define NWAY  2205      // 5*441
#define NPAD  2304      // 18*128
#define BN    128       // block n-tile
#define NT    18        // NPAD/BN
#define INV_Q2 (1.0f / 16129.0f)   // 1/127^2
#define NEGINF (-2147483647 - 1)

__device__ __forceinline__ void glds16(const void* g, void* l) {
  __builtin_amdgcn_global_load_lds(
      (__attribute__((address_space(1))) unsigned int*)g,
      (__attribute__((address_space(3))) unsigned int*)l, 16, 0, 0);
}

// 3-op sorted-top3 insert primitive: med3(v, hi, lo) == new lo-rank value.
__device__ __forceinline__ int med3i(int a, int b, int c) {
  int d;
  asm("v_med3_i32 %0, %1, %2, %3" : "=v"(d) : "v"(a), "v"(b), "v"(c));
  return d;
}

// ---------------------------------------------------------------------------
// Zero pad rows of A/B (int8 bytes) and the output accumulator.
// ---------------------------------------------------------------------------
__global__ void zero_pad(u8* __restrict__ A8, u8* __restrict__ S8,
                         float* __restrict__ out) {
  int i = blockIdx.x * 256 + threadIdx.x;
  if (i < 49280) {                                  // (MPAD-MROWS)*640 bytes
    A8[(size_t)MROWS * C_DIM + i] = 0;
    return;
  }
  i -= 49280;
  if (i < 316800) {                                 // 5*(NPAD-NWAY)*640 bytes
    const int w = i / 63360;
    const int r = i % 63360;
    S8[((size_t)w * NPAD + NWAY) * C_DIM + r] = 0;
    return;
  }
  i -= 316800;
  if (i < QN * WAYS) out[i] = 0.f;
}

// ---------------------------------------------------------------------------
// Normalize each (img, hw) descriptor over C, scale by 127, emit int8,
// transposed to [row][c] (c contiguous, 640 B/row). (unchanged)
// ---------------------------------------------------------------------------
__global__ __launch_bounds__(256)
void prep_norm_transpose(const float* __restrict__ src, u8* __restrict__ dst,
                         int support) {
  const int bid = blockIdx.x;
  const int img = bid / 7;
  const int mt = bid % 7;
  const int m0 = mt * 64;
  const int t = threadIdx.x;
  const int mloc = t & 63;
  const int cpart = t >> 6;                 // 0..3
  const int m = m0 + mloc;
  const int m_eff = (m < HW_DIM) ? m : (HW_DIM - 1);
  const float* base = src + (size_t)img * (C_DIM * HW_DIM);

  float ss = 0.f;
  const int c0 = cpart * 160;
  for (int c = c0; c < c0 + 160; ++c) {
    float v = base[(size_t)c * HW_DIM + m_eff];
    ss += v * v;
  }
  __shared__ float red[256];
  __shared__ float inv[64];
  red[t] = ss;
  __syncthreads();
  if (t < 64) {
    float s4 = red[t] + red[t + 64] + red[t + 128] + red[t + 192];
    inv[t] = rsqrtf(s4) * 127.0f;
  }
  __syncthreads();

  size_t drow0;
  if (support) {
    const int w = img / 5, shot = img % 5;
    drow0 = (size_t)w * NPAD + (size_t)shot * HW_DIM;
  } else {
    drow0 = (size_t)img * HW_DIM;
  }

  __shared__ __align__(16) u8 T[64][80];    // 64 data + 16 pad per row
  const float iv = inv[mloc];
  const int mw = t >> 2;
  const int cg = t & 3;
  const int m_out = m0 + mw;

  for (int ct = 0; ct < 10; ++ct) {
    int q[16];
#pragma unroll
    for (int ci = 0; ci < 16; ++ci) {
      const int c = ct * 64 + cpart * 16 + ci;
      q[ci] = __float2int_rn(base[(size_t)c * HW_DIM + m_eff] * iv);
    }
    __syncthreads();                        // previous tile fully consumed
    uint4 w;
    w.x = (q[0] & 255) | ((q[1] & 255) << 8) | ((q[2] & 255) << 16) | ((q[3] & 255) << 24);
    w.y = (q[4] & 255) | ((q[5] & 255) << 8) | ((q[6] & 255) << 16) | ((q[7] & 255) << 24);
    w.z = (q[8] & 255) | ((q[9] & 255) << 8) | ((q[10] & 255) << 16) | ((q[11] & 255) << 24);
    w.w = (q[12] & 255) | ((q[13] & 255) << 8) | ((q[14] & 255) << 16) | ((q[15] & 255) << 24);
    *(uint4*)&T[mloc][cpart * 16] = w;
    __syncthreads();
    if (m_out < HW_DIM) {
      const uint4 v = *(const uint4*)&T[mw][cg * 16];
      *(uint4*)(dst + (drow0 + m_out) * C_DIM + ct * 64 + cg * 16) = v;
    }
  }
}

// ---------------------------------------------------------------------------
// Fused cosine-sim GEMM + per-row top-3 + sum -- Round-15 structure.
// KEY CHANGE: mfma_i32_16x16x64_i8 instead of 32x32x32.
//  - The 128-arch-VGPR wall at 2 blocks/CU (R2/R6/R7: compiler always
//    lands arch=128 at (256,2), rest spills) killed every 32x32 variant
//    with 64 m-rows/wave: top-3 state alone was 96 regs (32 row-slots).
//  - 16x16 C-layout: lane covers only 4 rows/tile (row=(lane>>4)*4+reg,
//    col=lane&15). Wave tile 64m x 64n = 4x4 tiles -> 16 row-slots ->
//    t*[16] = 48 regs. Arch total: t3 48 + a[4][2] 32 + Aptr 8 + Boff 6
//    + temps ~20 ~= 114 <= 128 -> the R0-proven no-spill class.
//  - B-frag reuse x4 (each B frag feeds 4 m-tiles): 8 ds_read_b128 per
//    wave-phase for 32 MFMAs (0.25 reads/MFMA, 2x better than R7).
//  - 2 blocks/CU via (256,2): two staggered barrier domains -- the only
//    mechanism that has ever amortized the ~3900-cyc phase latency
//    (R0 throughput 2093/phase vs R4 solo 3871).
//  - A streamed per kt from L2 (R4-proven: FETCH stays ~106 MB), single
//    buffer, reloaded after the MFMA burst (WAR-safe).
// Grid: 5 ways * 259 m-chunks = 1295 blocks of 256 threads.
// ---------------------------------------------------------------------------
__global__ __launch_bounds__(256, 2)
void simtopk(const u8* __restrict__ A8, const u8* __restrict__ S8,
             float* __restrict__ out) {
  __shared__ __align__(16) u8 Bs[2][BN * 128];      // 32 KB B double buffer
  __shared__ float qsum[2];

  const int bid = blockIdx.x;
  const int way = bid / MBLK;
  const int mc = bid % MBLK;
  const int R0 = mc * MCH;
  const int tid = threadIdx.x;
  const int lane = tid & 63;
  const int wv = tid >> 6;                  // 0..3
  const int wm = (wv >> 1) * 64;            // wave m base: 0 / 64
  const int nh = wv & 1;                    // n-half: 0 / 1
  const int wnB = nh * 64;                  // wave n base within BN=128
  const int cl = lane & 15;                 // 16x16 col / A row lane
  const int kq = lane >> 4;                 // k-quarter selector (0..3)

  if (tid < 2) qsum[tid] = 0.f;

  const u8* Sway = S8 + (size_t)way * NPAD * C_DIM;

  // ---- A row base pointers: lane owns row (R0+wm+mt*16+cl), k-bytes
  // kq*16..+16 of each 64-B k-subtile. kt*128+s*64 fits the 13-bit imm.
  const u8* Ar[4];
#pragma unroll
  for (int mt = 0; mt < 4; ++mt)
    Ar[mt] = A8 + (size_t)(R0 + wm + mt * 16 + cl) * C_DIM + kq * 16;

  // Single A buffer for current kt: a[mtile][s] (4x2 i32x4 = 32 regs).
  i32x4 a[4][2];
#pragma unroll
  for (int mt = 0; mt < 4; ++mt)
#pragma unroll
    for (int s = 0; s < 2; ++s)
      a[mt][s] = *(const i32x4*)(Ar[mt] + s * 64);

  // ---- B staging: strip = 8 rows x 128 B = 1 KB per glds16;
  // 16 strips per phase (BN=128), 4 per wave. Source-side XOR swizzle:
  // LDS slot j of row r holds source chunk j^(r&7).
  const unsigned brow =
      (unsigned)((lane >> 3) * 640 + (((lane & 7) ^ (lane >> 3)) * 16));
#pragma unroll
  for (int j = 0; j < 4; ++j) {             // prologue: phase 0 -> Bs[0]
    const int st = wv * 4 + j;
    glds16(Sway + (unsigned)st * (8 * 640) + brow, Bs[0] + st * 1024);
  }

  // ---- B-frag LDS offsets: row = wnB + ntl*16 + cl; 16-B chunk within
  // the 128-B phase stripe = (s*4+kq) ^ (row&7) = (s*4+kq) ^ (cl&7).
  int bBase[4], sx[2];
#pragma unroll
  for (int ntl = 0; ntl < 4; ++ntl)
    bBase[ntl] = (wnB + ntl * 16 + cl) * 128;
#pragma unroll
  for (int s = 0; s < 2; ++s)
    sx[s] = ((s * 4 + kq) ^ (cl & 7)) * 16;

  i32x4 acc[4][4];                          // [mtile][ntile], 64 regs (AGPR)
#pragma unroll
  for (int mt = 0; mt < 4; ++mt)
#pragma unroll
    for (int ntl = 0; ntl < 4; ++ntl)
#pragma unroll
      for (int g = 0; g < 4; ++g) acc[mt][ntl][g] = 0;

  int t0[16], t1[16], t2[16];               // per-lane top-3, 16 row slots
#pragma unroll
  for (int r = 0; r < 16; ++r) { t0[r] = NEGINF; t1[r] = NEGINF; t2[r] = NEGINF; }

  int p = 0;
  for (int nt = 0; nt < NT; ++nt) {
#pragma unroll
    for (int kt = 0; kt < 5; ++kt) {
      __syncthreads();  // Bs[p] staged & a[] loaded (drained by barrier)

      const bool lastph = (nt == NT - 1) && (kt == 4);
      const int kt1 = (kt == 4) ? 0 : kt + 1;

      if (!lastph) {    // B prefetch next phase -> Bs[p^1]
        const int nt1 = (kt == 4) ? nt + 1 : nt;
        const unsigned off =
            (unsigned)nt1 * (BN * C_DIM) + (unsigned)(kt1 * 128);
#pragma unroll
        for (int j = 0; j < 4; ++j) {
          const int st = wv * 4 + j;
          glds16(Sway + (unsigned)st * (8 * 640) + brow + off,
                 Bs[p ^ 1] + st * 1024);
        }
      }

      const u8* Bp = Bs[p];
#pragma unroll
      for (int s = 0; s < 2; ++s)
#pragma unroll
        for (int ntl = 0; ntl < 4; ++ntl) {
          const i32x4 b = *(const i32x4*)(Bp + bBase[ntl] + sx[s]);
          acc[0][ntl] = __builtin_amdgcn_mfma_i32_16x16x64_i8(a[0][s], b, acc[0][ntl], 0, 0, 0);
          acc[1][ntl] = __builtin_amdgcn_mfma_i32_16x16x64_i8(a[1][s], b, acc[1][ntl], 0, 0, 0);
          acc[2][ntl] = __builtin_amdgcn_mfma_i32_16x16x64_i8(a[2][s], b, acc[2][ntl], 0, 0, 0);
          acc[3][ntl] = __builtin_amdgcn_mfma_i32_16x16x64_i8(a[3][s], b, acc[3][ntl], 0, 0, 0);
        }

      if (!lastph) {    // A load for kt1 (WAR-safe: after all MFMA reads)
#pragma unroll
        for (int mt = 0; mt < 4; ++mt)
#pragma unroll
          for (int s = 0; s < 2; ++s)
            a[mt][s] = *(const i32x4*)(Ar[mt] + kt1 * 128 + s * 64);
      }
      p ^= 1;
    }

    // end of nt: top-3 insert. 16x16 C/D: col = cl, row = kq*4 + g
    // (+ mt*16 + wm). 4 candidates per slot (one per ntile).
    if (nt != NT - 1) {
#pragma unroll
      for (int mt = 0; mt < 4; ++mt)
#pragma unroll
        for (int ntl = 0; ntl < 4; ++ntl)
#pragma unroll
          for (int g = 0; g < 4; ++g) {
            const int v = acc[mt][ntl][g];
            const int r = mt * 4 + g;
            t2[r] = med3i(v, t1[r], t2[r]);
            t1[r] = med3i(v, t0[r], t1[r]);
            t0[r] = max(t0[r], v);
            acc[mt][ntl][g] = 0;
          }
    } else {                                // last tile: mask pad columns
#pragma unroll
      for (int mt = 0; mt < 4; ++mt)
#pragma unroll
        for (int ntl = 0; ntl < 4; ++ntl) {
          const int ncol = nt * BN + wnB + ntl * 16 + cl;
          const bool bad = (ncol >= NWAY);
#pragma unroll
          for (int g = 0; g < 4; ++g) {
            int v = acc[mt][ntl][g];
            if (bad) v = NEGINF;
            const int r = mt * 4 + g;
            t2[r] = med3i(v, t1[r], t2[r]);
            t1[r] = med3i(v, t0[r], t1[r]);
            t0[r] = max(t0[r], v);
          }
        }
    }
  }

  // ---- butterfly over the 16 column-lanes (d = 1,2,4,8): after this all
  // cl-lanes hold the per-row top-3 merged across this wave's 64 n-cols.
#pragma unroll
  for (int d = 1; d <= 8; d <<= 1) {
#pragma unroll
    for (int r = 0; r < 16; ++r) {
      const int o0 = __shfl_xor(t0[r], d);
      const int o1 = __shfl_xor(t1[r], d);
      const int o2 = __shfl_xor(t2[r], d);
      t2[r] = med3i(o0, t1[r], t2[r]);
      t1[r] = med3i(o0, t0[r], t1[r]);
      t0[r] = max(t0[r], o0);
      t2[r] = med3i(o1, t1[r], t2[r]);
      t1[r] = med3i(o1, t0[r], t1[r]);
      t0[r] = max(t0[r], o1);
      t2[r] = med3i(o2, t1[r], t2[r]);
      t1[r] = med3i(o2, t0[r], t1[r]);
      t0[r] = max(t0[r], o2);
    }
  }

  // ---- dump per-(nh) row partials to LDS aliased over Bs: 2 x 128 x
  // i32x4 = 4 KB. Lane cl==0 of each kq writes its 16 rows.
  __syncthreads();                          // all B-tile reads complete
  i32x4* part = (i32x4*)&Bs[0][0];          // part[nh*128 + row]
  if (cl == 0) {
#pragma unroll
    for (int mt = 0; mt < 4; ++mt)
#pragma unroll
      for (int g = 0; g < 4; ++g) {
        const int row_local = wm + mt * 16 + kq * 4 + g;
        i32x4 v;
        v[0] = t0[mt * 4 + g]; v[1] = t1[mt * 4 + g];
        v[2] = t2[mt * 4 + g]; v[3] = NEGINF;
        part[nh * MCH + row_local] = v;
      }
  }
  __syncthreads();
  if (tid < MCH) {
    const int grow = R0 + tid;
    if (grow < MROWS) {
      const i32x4 va = part[tid];
      const i32x4 vb = part[MCH + tid];
      int a0_ = va[0], a1_ = va[1], a2_ = va[2];
      a2_ = med3i(vb[0], a1_, a2_); a1_ = med3i(vb[0], a0_, a1_); a0_ = max(a0_, vb[0]);
      a2_ = med3i(vb[1], a1_, a2_); a1_ = med3i(vb[1], a0_, a1_); a0_ = max(a0_, vb[1]);
      a2_ = med3i(vb[2], a1_, a2_); a1_ = med3i(vb[2], a0_, a1_); a0_ = max(a0_, vb[2]);
      const float rs = (float)(a0_ + a1_ + a2_) * INV_Q2;
      const int qq = grow / HW_DIM;
      atomicAdd(&qsum[qq - (R0 / HW_DIM)], rs);     // block spans <= 2 q's
    }
  }
  __syncthreads();
  if (tid < 2) {
    const int qq = R0 / HW_DIM + tid;
    if (qq < QN) atomicAdd(out + qq * WAYS + way, qsum[tid]);
  }
}

// ---------------------------------------------------------------------------
extern "C" void kernel_launch(void* const* d_in, const int* in_sizes, int n_in,
                              void* d_out, int out_size, void* d_ws, size_t ws_size,
                              hipStream_t stream) {
  const float* x1 = (const float*)d_in[0];
  const float* x2 = (const float*)d_in[1];
  float* out = (float*)d_out;
  u8* A8 = (u8*)d_ws;                                        // MPAD x 640 i8
  u8* S8 = (u8*)d_ws + (size_t)MPAD * C_DIM;                 // 5 x NPAD x 640

  hipLaunchKernelGGL(zero_pad, dim3(1432), dim3(256), 0, stream, A8, S8, out);
  hipLaunchKernelGGL(prep_norm_transpose, dim3(QN * 7), dim3(256), 0, stream,
                     x1, A8, 0);
  hipLaunchKernelGGL(prep_norm_transpose, dim3(SN * 7), dim3(256), 0, stream,
                     x2, S8, 1);
  hipLaunchKernelGGL(simtopk, dim3(WAYS * MBLK), dim3(256), 0, stream,
                     A8, S8, out);
}